// Round 16
// baseline (54.178 us; speedup 1.0000x reference)
//
#include <hip/hip_runtime.h>

#define NB 8
#define NA 32768
#define NC 80
#define NM 32
#define NK 50
#define CAP 2048
#define QA (NA / 4)            // 8192 anchors per pos-quarter
#define NBLK 2048              // mega grid: 1024 pos-quarter + 512 t2 + 512 f0-only
#define TPC 64                 // t2 chunks per image (512 anchors each)
#define CORRB (NA / 256)       // 128 corr blocks per image
constexpr float VAR0 = 0.1f, VAR1 = 0.2f;
constexpr float T1f  = 0.5f;
constexpr float SL1B = 0.11f;
constexpr float SL1W = 0.75f;
constexpr float FEPS = 1e-12f;

__device__ __forceinline__ float fast_rcp(float x) { return __builtin_amdgcn_rcpf(x); }

// IoU with hardware rcp — ONE shared inline so t2/corr recomputation is bit-identical.
__device__ __forceinline__ float iou_corner(float tx0, float ty0, float tx1, float ty1, float ta,
                                            float bx0, float by0, float bx1, float by1, float ba) {
  float lx = fmaxf(tx0, bx0), ly = fmaxf(ty0, by0);
  float rx = fminf(tx1, bx1), ry = fminf(ty1, by1);
  float wx = fmaxf(rx - lx, 0.f), wy = fmaxf(ry - ly, 0.f);
  float inter = wx * wy;
  return inter * fast_rcp(ta + ba - inter);
}

// f0(x) = s^2 * min(-log(1-s),100), s=sigmoid(x); analytic: -log(1-s) = x + log(1+e^-x)
__device__ __forceinline__ float f0_term(float x) {
  x = fmaxf(x, -60.f);
  float e = __expf(-x);
  float d = 1.f + e;
  float s = fast_rcp(d);
  float L = x + __logf(d);
  return s * s * fminf(L, 100.f);
}

__device__ __forceinline__ float f0_4(float4 v) {
  return f0_term(v.x) + f0_term(v.y) + f0_term(v.z) + f0_term(v.w);
}

// ---- K1: all blocks f0 slice; roles: pos-quarter | t2 | f0-only (512-thread blocks) ----
__global__ void __launch_bounds__(512) mega_kernel(const float4* __restrict__ br,
                                                   const float* __restrict__ cls,
                                                   const float4* __restrict__ anc,
                                                   const float4* __restrict__ tgt,
                                                   unsigned* __restrict__ partmax,
                                                   unsigned* __restrict__ pairmask,
                                                   unsigned long long* __restrict__ cand50,
                                                   unsigned* __restrict__ poscnt,
                                                   unsigned* __restrict__ zlist,
                                                   unsigned* __restrict__ zcnt,
                                                   float* __restrict__ f0part) {
  __shared__ int hist[512];
  __shared__ unsigned long long cand[CAP];
  __shared__ int s_cnt, s_B1, s_filled, s_zc;
  __shared__ unsigned char s_flag[512];
  __shared__ unsigned s_max[NM];
  __shared__ float4 s_t[NM];
  __shared__ float s_ta[NM];
  __shared__ float swave[8];

  int bx = blockIdx.x;
  int tid = threadIdx.x;

  // ===== phase A (all 2048 blocks): f0 slice, 5 float4/thread =====
  {
    const float4* cls4 = (const float4*)cls;
    constexpr int STRIDE = NBLK * 512;   // 1,048,576; NTOT4/STRIDE == 5 exactly
    int base = bx * 512 + tid;
    float4 v0 = cls4[base + 0 * STRIDE];
    float4 v1 = cls4[base + 1 * STRIDE];
    float4 v2 = cls4[base + 2 * STRIDE];
    float4 v3 = cls4[base + 3 * STRIDE];
    float4 v4 = cls4[base + 4 * STRIDE];
    float accum = f0_4(v0) + f0_4(v1) + f0_4(v2) + f0_4(v3) + f0_4(v4);
    for (int off = 32; off; off >>= 1) accum += __shfl_down(accum, off);
    if ((tid & 63) == 0) swave[tid >> 6] = accum;
    __syncthreads();
    if (tid == 0) {
      float s = 0.f;
#pragma unroll
      for (int i = 0; i < 8; ++i) s += swave[i];
      f0part[bx] = s;                    // non-atomic partial
    }
    __syncthreads();
  }

  if (bx < 4 * NB * NM) {
    // ===== pos-quarter role: register-cached IoUs (computed once), exact local top-50 =====
    int bm = bx >> 2;
    int q = bx & 3;
    int abase = q * QA;
    float4 t = tgt[bm];
    float ta = (t.z - t.x) * (t.w - t.y);

    hist[tid] = 0;
    if (tid == 0) s_cnt = 0;
    __syncthreads();

    float riou[16];
    unsigned mask = 0u;
#pragma unroll
    for (int k = 0; k < 16; ++k) {
      float4 p = anc[abase + tid + (k << 9)];
      float hx = 0.5f * p.z, hy = 0.5f * p.w;
      float x0 = p.x - hx, y0 = p.y - hy, x1 = p.x + hx, y1 = p.y + hy;
      float ba = (x1 - x0) * (y1 - y0);
      float v = iou_corner(t.x, t.y, t.z, t.w, ta, x0, y0, x1, y1, ba);
      riou[k] = v;
      if (v > 0.f) {
        mask |= 1u << k;
        atomicAdd(&hist[(int)(__float_as_uint(v) >> 21)], 1);
      }
    }
    __syncthreads();

    if (tid == 0) {
      int cum = 0, b1 = 0;
      for (int bin = 511; bin >= 0; --bin) {
        cum += hist[bin];
        if (cum >= NK) { b1 = bin; break; }
      }
      s_B1 = b1;
      s_filled = cum;
    }
    __syncthreads();
    int B1 = s_B1;
    int local_pos = s_filled;            // exact when <NK, else >=NK
    if (tid == 0) poscnt[bm * 4 + q] = (unsigned)min(local_pos, NK);

    // ballot-compacted candidate collection (1 atomic/wave/k)
    int lane = tid & 63;
#pragma unroll
    for (int k = 0; k < 16; ++k) {
      float v = riou[k];
      bool want = (v > 0.f) && ((int)(__float_as_uint(v) >> 21) >= B1);
      unsigned long long ball = __ballot(want);
      if (ball) {
        int lead = __ffsll((long long)ball) - 1;
        int base = 0;
        if (lane == lead) base = atomicAdd(&s_cnt, __popcll(ball));
        base = __shfl(base, lead);
        if (want) {
          int slot = base + __popcll(ball & ((1ull << lane) - 1ull));
          if (slot < CAP)
            cand[slot] = ((unsigned long long)__float_as_uint(v) << 32)
                         | (unsigned)(~(abase + tid + (k << 9)));
        }
      }
    }
    __syncthreads();
    int n = min(s_cnt, CAP);

    for (int c = tid; c < n; c += 512) {
      unsigned long long key = cand[c];
      int rank = 0;
      for (int j = 0; j < n; ++j) rank += (cand[j] > key);
      if (rank < NK) cand50[(size_t)(bm * 4 + q) * NK + rank] = key;
    }
    int nw = min(n, NK);
    if (tid >= nw && tid < NK)
      cand50[(size_t)(bm * 4 + q) * NK + tid] = 0ull;

    if (local_pos < NK) {
      if (tid == 0) s_zc = 0;
      __syncthreads();
#pragma unroll
      for (int k = 0; k < 16; ++k) {
        s_flag[tid] = ((mask >> k) & 1u) == 0u;
        __syncthreads();
        if (tid == 0) {
          for (int i = 0; i < 512 && s_zc < NK; ++i)
            if (s_flag[i]) zlist[(size_t)(bm * 4 + q) * NK + s_zc++] = abase + (k << 9) + i;
        }
        __syncthreads();
      }
      if (tid == 0) zcnt[bm * 4 + q] = (unsigned)s_zc;
    }

  } else if (bx < 4 * NB * NM + TPC * NB) {
    // ===== t2 role: decode one (b,a) per thread; per-(b,m) partial max; pairmask =====
    int t2i = bx - 4 * NB * NM;
    int b = t2i >> 6;                    // 64 chunks per image
    int chunk = t2i & 63;
    if (tid < NM) {
      float4 t = tgt[b * NM + tid];
      s_t[tid] = t;
      s_ta[tid] = (t.z - t.x) * (t.w - t.y);
      s_max[tid] = 0u;
    }
    __syncthreads();

    int a = chunk * 512 + tid;
    float4 p = anc[a];
    float4 l = br[(size_t)b * NA + a];
    float cx = p.x + l.x * VAR0 * p.z;
    float cy = p.y + l.y * VAR0 * p.w;
    float w = p.z * __expf(l.z * VAR1);
    float h = p.w * __expf(l.w * VAR1);
    float dx0 = cx - 0.5f * w, dy0 = cy - 0.5f * h;
    float dx1 = cx + 0.5f * w, dy1 = cy + 0.5f * h;
    float da = (dx1 - dx0) * (dy1 - dy0);

    unsigned mymask = 0u;
#pragma unroll
    for (int mm = 0; mm < NM; ++mm) {
      int m = (tid + mm) & (NM - 1);     // stagger over LDS bins
      float4 t = s_t[m];
      float iou = iou_corner(t.x, t.y, t.z, t.w, s_ta[m], dx0, dy0, dx1, dy1, da);
      if (iou > T1f) mymask |= 1u << m;
      atomicMax(&s_max[m], __float_as_uint(iou));  // iou>=0: uint order == float order
    }
    pairmask[(size_t)b * NA + a] = mymask;
    __syncthreads();
    if (tid < NM)
      partmax[((size_t)b * NM + tid) * TPC + chunk] = s_max[tid];  // non-atomic
  }
  // else: f0-only
}

// ---- K2: merge four local top-50s -> exact top-50 + bag loss ----
__global__ void __launch_bounds__(256) posfin_kernel(const float4* __restrict__ br,
                                                     const float* __restrict__ cls,
                                                     const float4* __restrict__ anc,
                                                     const float4* __restrict__ tgt,
                                                     const int* __restrict__ labels,
                                                     const unsigned long long* __restrict__ cand50,
                                                     const unsigned* __restrict__ poscnt,
                                                     const unsigned* __restrict__ zlist,
                                                     const unsigned* __restrict__ zcnt,
                                                     float* __restrict__ posp) {
  __shared__ unsigned long long kbuf[4 * NK];
  __shared__ int sel[NK];
  __shared__ int s_total;
  int bm = blockIdx.x;
  int b = bm >> 5;
  int tid = threadIdx.x;
  float4 t = tgt[bm];

  if (tid < 4 * NK)
    kbuf[tid] = cand50[(size_t)bm * 4 * NK + tid];   // quarters stored contiguously
  if (tid == 0)
    s_total = (int)(poscnt[bm * 4] + poscnt[bm * 4 + 1] +
                    poscnt[bm * 4 + 2] + poscnt[bm * 4 + 3]);   // exact when < NK
  __syncthreads();

  if (tid < 4 * NK) {
    unsigned long long key = kbuf[tid];
    if (key != 0ull) {                   // real candidates rank above sentinels
      int rank = 0;
      for (int j = 0; j < 4 * NK; ++j) rank += (kbuf[j] > key);
      if (rank < NK) sel[rank] = (int)(~(unsigned)(key & 0xFFFFFFFFull));
    }
  }
  __syncthreads();

  int total = s_total;
  if (total < NK) {                      // degenerate: fill with smallest zero-iou idx
    if (tid == 0) {
      int idx = total;
      for (int qq = 0; qq < 4 && idx < NK; ++qq) {
        unsigned zc = zcnt[bm * 4 + qq];
        for (unsigned j = 0; j < zc && idx < NK; ++j)
          sel[idx++] = (int)zlist[(size_t)(bm * 4 + qq) * NK + j];
      }
    }
    __syncthreads();
  }

  if (tid < 64) {
    int lane = tid;
    float lg = 0.f, wr = 0.f;
    if (lane < NK) {
      int a = sel[lane];
      int lb = labels[bm];
      float4 p = anc[a];
      float4 l = br[(size_t)b * NA + a];
      float logit = cls[((size_t)b * NA + a) * NC + lb];
      float mc = fast_rcp(1.f + __expf(-logit));
      float gx = ((t.x + t.z) * 0.5f - p.x) * fast_rcp(VAR0 * p.z);
      float gy = ((t.y + t.w) * 0.5f - p.y) * fast_rcp(VAR0 * p.w);
      float gw = __logf((t.z - t.x) * fast_rcp(p.z)) * 5.f;   // /VAR1
      float gh = __logf((t.w - t.y) * fast_rcp(p.w)) * 5.f;
      float v0 = gx - l.x, v1 = gy - l.y, v2 = gw - l.z, v3 = gh - l.w;
      float rl = 0.f;
      {
        float av;
        av = fabsf(v0); rl += (av < SL1B) ? (0.5f / SL1B) * v0 * v0 : (av - 0.5f * SL1B);
        av = fabsf(v1); rl += (av < SL1B) ? (0.5f / SL1B) * v1 * v1 : (av - 0.5f * SL1B);
        av = fabsf(v2); rl += (av < SL1B) ? (0.5f / SL1B) * v2 * v2 : (av - 0.5f * SL1B);
        av = fabsf(v3); rl += (av < SL1B) ? (0.5f / SL1B) * v3 * v3 : (av - 0.5f * SL1B);
      }
      rl *= SL1W;
      lg = mc * __expf(-rl);
      wr = fast_rcp(fmaxf(1.f - lg, FEPS));
    }
    float swl = wr * lg, swr = wr;
    for (int off = 32; off; off >>= 1) { swl += __shfl_down(swl, off); swr += __shfl_down(swr, off); }
    if (lane == 0) {
      float bag = swl / swr;
      posp[bm] = -fmaxf(logf(fmaxf(bag, 1e-38f)), -100.f);    // non-atomic partial
    }
  }
}

// ---- K3: sparse correction where bp > 0 (non-atomic partials) ----
__global__ void __launch_bounds__(256) corr_kernel(const float4* __restrict__ br,
                                                   const float* __restrict__ cls,
                                                   const float4* __restrict__ anc,
                                                   const float4* __restrict__ tgt,
                                                   const int* __restrict__ labels,
                                                   const unsigned* __restrict__ partmax,
                                                   const unsigned* __restrict__ pairmask,
                                                   float* __restrict__ corrp) {
  __shared__ float4 s_t[NM];
  __shared__ float s_ta[NM], s_inv[NM];
  __shared__ unsigned s_cmask[NC];
  __shared__ unsigned s_maxm[NM];
  __shared__ unsigned s_slotmask[NM];
  __shared__ int s_slotclass[NM];
  __shared__ int s_nslots;
  int b = blockIdx.y;
  int tid = threadIdx.x;
  if (tid < NC) s_cmask[tid] = 0u;
  if (tid < NM) s_maxm[tid] = 0u;
  if (tid == 0) s_nslots = 0;
  __syncthreads();
  if (tid < NM) {
    float4 t = tgt[b * NM + tid];
    s_t[tid] = t;
    s_ta[tid] = (t.z - t.x) * (t.w - t.y);
    atomicOr(&s_cmask[labels[b * NM + tid]], 1u << tid);
  }
  {
    int m = tid >> 3, j = tid & 7;
    const unsigned* pm = &partmax[((size_t)b * NM + m) * TPC];
    unsigned mx = 0u;
    for (int k = j; k < TPC; k += 8) mx = max(mx, pm[k]);
    atomicMax(&s_maxm[m], mx);
  }
  __syncthreads();
  if (tid < NM) {
    float mxf = __uint_as_float(s_maxm[tid]);
    s_inv[tid] = 1.0f / (fmaxf(mxf, T1f) - T1f);   // T1+1e-12 rounds to 0.5f in fp32
  }
  __syncthreads();
  if (tid < NC && s_cmask[tid] != 0u) {
    int slot = atomicAdd(&s_nslots, 1);
    s_slotmask[slot] = s_cmask[tid];
    s_slotclass[slot] = tid;
  }
  __syncthreads();
  int nslots = s_nslots;

  int a = blockIdx.x * 256 + tid;
  unsigned mk32 = pairmask[(size_t)b * NA + a];
  float accum = 0.f;
  if (mk32) {
    float4 p = anc[a];
    float4 l = br[(size_t)b * NA + a];
    float cx = p.x + l.x * VAR0 * p.z;
    float cy = p.y + l.y * VAR0 * p.w;
    float w = p.z * __expf(l.z * VAR1);
    float h = p.w * __expf(l.w * VAR1);
    float dx0 = cx - 0.5f * w, dy0 = cy - 0.5f * h;
    float dx1 = cx + 0.5f * w, dy1 = cy + 0.5f * h;
    float da = (dx1 - dx0) * (dy1 - dy0);
    for (int j = 0; j < nslots; ++j) {
      unsigned sm = mk32 & s_slotmask[j];
      if (!sm) continue;
      float bp = 0.f;
      while (sm) {
        int m = __ffs(sm) - 1;
        sm &= sm - 1;
        float4 t = s_t[m];
        float iou = iou_corner(t.x, t.y, t.z, t.w, s_ta[m], dx0, dy0, dx1, dy1, da);
        float o = (iou - T1f) * s_inv[m];
        bp = fmaxf(bp, fminf(fmaxf(o, 0.f), 1.f));
      }
      if (bp > 0.f) {
        float x = cls[((size_t)b * NA + a) * NC + s_slotclass[j]];
        float s = fast_rcp(1.f + __expf(-fmaxf(x, -60.f)));
        float pr = s * (1.f - bp);
        float om = fmaxf(1.f - pr, 1e-38f);
        float fbp = pr * pr * fminf(-__logf(om), 100.f);
        accum += fbp - f0_term(x);       // cancels mega's baseline bit-exactly
      }
    }
  }
  for (int off = 32; off; off >>= 1) accum += __shfl_down(accum, off);
  __shared__ float swv[4];
  if ((tid & 63) == 0) swv[tid >> 6] = accum;
  __syncthreads();
  if (tid == 0)
    corrp[(size_t)b * CORRB + blockIdx.x] = swv[0] + swv[1] + swv[2] + swv[3];  // non-atomic
}

// ---- K4: finalize — sum all partials in double ----
__global__ void __launch_bounds__(256) fin_kernel(const float* __restrict__ posp,
                                                  const float* __restrict__ f0part,
                                                  const float* __restrict__ corrp,
                                                  float* __restrict__ out) {
  int tid = threadIdx.x;
  double sp = 0.0, sn = 0.0;
  for (int i = tid; i < NB * NM; i += 256) sp += (double)posp[i];
  for (int i = tid; i < NBLK; i += 256) sn += (double)f0part[i];
  for (int i = tid; i < NB * CORRB; i += 256) sn += (double)corrp[i];
  for (int off = 32; off; off >>= 1) { sp += __shfl_down(sp, off); sn += __shfl_down(sn, off); }
  __shared__ double swp[4], swn[4];
  if ((tid & 63) == 0) { swp[tid >> 6] = sp; swn[tid >> 6] = sn; }
  __syncthreads();
  if (tid == 0) {
    double pos = swp[0] + swp[1] + swp[2] + swp[3];
    double neg = swn[0] + swn[1] + swn[2] + swn[3];
    out[0] = (float)(pos / 256.0 * 0.5);
    out[1] = (float)(neg / 12800.0 * 0.5);
  }
}

extern "C" void kernel_launch(void* const* d_in, const int* in_sizes, int n_in,
                              void* d_out, int out_size, void* d_ws, size_t ws_size,
                              hipStream_t stream) {
  const float4* br  = (const float4*)d_in[0];
  const float*  cls = (const float*)d_in[1];
  const float4* anc = (const float4*)d_in[2];
  const float4* tgt = (const float4*)d_in[3];
  const int*    lab = (const int*)d_in[4];
  float* out = (float*)d_out;
  // ws layout — written-before-read every call (zlist/zcnt written & read under the
  // same input-dependent condition); no global atomics anywhere -> no init needed:
  float*              posp     = (float*)d_ws;                               // 256 f32
  float*              f0part   = (float*)((char*)d_ws + 4096);               // 2048 f32
  float*              corrp    = (float*)((char*)d_ws + 16384);              // 1024 f32
  unsigned*           poscnt   = (unsigned*)((char*)d_ws + 24576);           // 1024 u32
  unsigned*           partmax  = (unsigned*)((char*)d_ws + 32768);           // 8*32*64 u32 = 64 KB
  unsigned long long* cand50   = (unsigned long long*)((char*)d_ws + 131072);// 256*4*50 u64 = 400 KB
  unsigned*           zlist    = (unsigned*)((char*)d_ws + 540672);          // 256*4*50 u32 = 200 KB
  unsigned*           zcnt     = (unsigned*)((char*)d_ws + 745472);          // 1024 u32
  unsigned*           pairmask = (unsigned*)((char*)d_ws + 753664);          // NB*NA u32 = 1 MB

  mega_kernel<<<dim3(NBLK), 512, 0, stream>>>(
      br, cls, anc, tgt, partmax, pairmask, cand50, poscnt, zlist, zcnt, f0part);
  posfin_kernel<<<dim3(NB * NM), 256, 0, stream>>>(
      br, cls, anc, tgt, lab, cand50, poscnt, zlist, zcnt, posp);
  corr_kernel<<<dim3(CORRB, NB), 256, 0, stream>>>(br, cls, anc, tgt, lab, partmax, pairmask, corrp);
  fin_kernel<<<1, 256, 0, stream>>>(posp, f0part, corrp, out);
}

// Round 17
// 49.300 us; speedup vs baseline: 1.0989x; 1.0989x over previous
//
#include <hip/hip_runtime.h>

#define NB 8
#define NA 32768
#define NC 80
#define NM 32
#define NK 50
#define CAP 2048
#define TB 32                  // t2 chunks per image (1024 anchors each)
#define HALF_A (NA / 2)        // 16384 anchors per pos-sub
#define NBLK 1024              // mega grid: 512 pos-sub + 256 t2 + 256 f0-helper
#define CORRB (NA / 256)       // 128 corr blocks per image
constexpr float VAR0 = 0.1f, VAR1 = 0.2f;
constexpr float T1f  = 0.5f;
constexpr float SL1B = 0.11f;
constexpr float SL1W = 0.75f;
constexpr float FEPS = 1e-12f;

typedef float nfloat4 __attribute__((ext_vector_type(4)));

__device__ __forceinline__ float fast_rcp(float x) { return __builtin_amdgcn_rcpf(x); }

// nontemporal float4 load — no-allocate hint keeps the 84MB cls stream out of L2,
// preserving L2 residency for the hot 512KB anchors array.
__device__ __forceinline__ nfloat4 ldnt4(const float* p) {
  return __builtin_nontemporal_load((const nfloat4*)p);
}

// IoU with hardware rcp — ONE shared inline so t2/corr recomputation is bit-identical.
__device__ __forceinline__ float iou_corner(float tx0, float ty0, float tx1, float ty1, float ta,
                                            float bx0, float by0, float bx1, float by1, float ba) {
  float lx = fmaxf(tx0, bx0), ly = fmaxf(ty0, by0);
  float rx = fminf(tx1, bx1), ry = fminf(ty1, by1);
  float wx = fmaxf(rx - lx, 0.f), wy = fmaxf(ry - ly, 0.f);
  float inter = wx * wy;
  return inter * fast_rcp(ta + ba - inter);
}

// f0(x) = s^2 * min(-log(1-s),100), s=sigmoid(x); analytic: -log(1-s) = x + log(1+e^-x)
__device__ __forceinline__ float f0_term(float x) {
  x = fmaxf(x, -60.f);                  // keeps e finite; term ~1e-51 there anyway
  float e = __expf(-x);
  float d = 1.f + e;
  float s = fast_rcp(d);
  float L = x + __logf(d);              // == -log(1-s), no cancellation
  return s * s * fminf(L, 100.f);
}

__device__ __forceinline__ float f0_4(nfloat4 v) {
  return f0_term(v.x) + f0_term(v.y) + f0_term(v.z) + f0_term(v.w);
}

// ---- K1: all blocks f0 slice (contiguous, nontemporal); roles: pos-sub | t2 | f0-only ----
__global__ void __launch_bounds__(1024) mega_kernel(const float4* __restrict__ br,
                                                    const float* __restrict__ cls,
                                                    const float4* __restrict__ anc,
                                                    const float4* __restrict__ tgt,
                                                    unsigned* __restrict__ partmax,
                                                    unsigned* __restrict__ pairmask,
                                                    unsigned long long* __restrict__ cand50,
                                                    unsigned* __restrict__ poscnt,
                                                    unsigned* __restrict__ zlist,
                                                    unsigned* __restrict__ zcnt,
                                                    float* __restrict__ f0part) {
  __shared__ int hist[512];
  __shared__ unsigned long long cand[CAP];
  __shared__ int s_cnt, s_B1, s_filled, s_zc;
  __shared__ unsigned char s_flag[1024];
  __shared__ unsigned s_max[NM];
  __shared__ float4 s_t[NM];
  __shared__ float s_ta[NM];
  __shared__ float swave[16];

  int bx = blockIdx.x;
  int tid = threadIdx.x;

  // ===== phase A (all 1024 blocks): f0 slice — block-contiguous 80KB window,
  //       5 coalesced nontemporal float4 loads/thread (kills the 16MB pow2 stride) =====
  {
    // block bx owns float4s [bx*5120, bx*5120+5120); loads at +1024-float4 steps
    int base = bx * 5120 + tid;
    nfloat4 v0 = ldnt4(cls + 4 * (base + 0 * 1024));
    nfloat4 v1 = ldnt4(cls + 4 * (base + 1 * 1024));
    nfloat4 v2 = ldnt4(cls + 4 * (base + 2 * 1024));
    nfloat4 v3 = ldnt4(cls + 4 * (base + 3 * 1024));
    nfloat4 v4 = ldnt4(cls + 4 * (base + 4 * 1024));
    float accum = f0_4(v0) + f0_4(v1) + f0_4(v2) + f0_4(v3) + f0_4(v4);
    for (int off = 32; off; off >>= 1) accum += __shfl_down(accum, off);
    if ((tid & 63) == 0) swave[tid >> 6] = accum;
    __syncthreads();
    if (tid == 0) {
      float s = 0.f;
#pragma unroll
      for (int i = 0; i < 16; ++i) s += swave[i];
      f0part[bx] = s;                    // non-atomic partial
    }
    __syncthreads();
  }

  if (bx < 2 * NB * NM) {
    // ===== pos-sub role: register-cached IoUs (computed once), exact local top-50 =====
    int bm = bx >> 1;
    int half = bx & 1;
    int abase = half * HALF_A;
    float4 t = tgt[bm];
    float ta = (t.z - t.x) * (t.w - t.y);

    if (tid < 512) hist[tid] = 0;
    if (tid == 0) s_cnt = 0;
    __syncthreads();

    float riou[16];
    unsigned mask = 0u;
#pragma unroll
    for (int k = 0; k < 16; ++k) {
      float4 p = anc[abase + tid + (k << 10)];
      float hx = 0.5f * p.z, hy = 0.5f * p.w;
      float x0 = p.x - hx, y0 = p.y - hy, x1 = p.x + hx, y1 = p.y + hy;
      float ba = (x1 - x0) * (y1 - y0);
      float v = iou_corner(t.x, t.y, t.z, t.w, ta, x0, y0, x1, y1, ba);
      riou[k] = v;
      if (v > 0.f) {
        mask |= 1u << k;
        atomicAdd(&hist[(int)(__float_as_uint(v) >> 21)], 1);
      }
    }
    __syncthreads();

    if (tid == 0) {
      int cum = 0, b1 = 0;
      for (int bin = 511; bin >= 0; --bin) {
        cum += hist[bin];
        if (cum >= NK) { b1 = bin; break; }
      }
      s_B1 = b1;
      s_filled = cum;
    }
    __syncthreads();
    int B1 = s_B1;
    int local_pos = s_filled;
    if (tid == 0) poscnt[bm * 2 + half] = (unsigned)min(local_pos, NK);

    // ballot-compacted candidate collection (1 atomic/wave/k)
    int lane = tid & 63;
#pragma unroll
    for (int k = 0; k < 16; ++k) {
      float v = riou[k];
      bool want = (v > 0.f) && ((int)(__float_as_uint(v) >> 21) >= B1);
      unsigned long long ball = __ballot(want);
      if (ball) {
        int lead = __ffsll((long long)ball) - 1;
        int base = 0;
        if (lane == lead) base = atomicAdd(&s_cnt, __popcll(ball));
        base = __shfl(base, lead);
        if (want) {
          int slot = base + __popcll(ball & ((1ull << lane) - 1ull));
          if (slot < CAP)
            cand[slot] = ((unsigned long long)__float_as_uint(v) << 32)
                         | (unsigned)(~(abase + tid + (k << 10)));
        }
      }
    }
    __syncthreads();
    int n = min(s_cnt, CAP);

    for (int c = tid; c < n; c += 1024) {
      unsigned long long key = cand[c];
      int rank = 0;
      for (int j = 0; j < n; ++j) rank += (cand[j] > key);
      if (rank < NK) cand50[(size_t)(bm * 2 + half) * NK + rank] = key;
    }
    int nw = min(n, NK);
    if (tid >= nw && tid < NK)
      cand50[(size_t)(bm * 2 + half) * NK + tid] = 0ull;

    if (local_pos < NK) {
      if (tid == 0) s_zc = 0;
      __syncthreads();
#pragma unroll
      for (int k = 0; k < 16; ++k) {
        s_flag[tid] = ((mask >> k) & 1u) == 0u;
        __syncthreads();
        if (tid == 0) {
          for (int i = 0; i < 1024 && s_zc < NK; ++i)
            if (s_flag[i]) zlist[(size_t)(bm * 2 + half) * NK + s_zc++] = abase + (k << 10) + i;
        }
        __syncthreads();
      }
      if (tid == 0) zcnt[bm * 2 + half] = (unsigned)s_zc;
    }

  } else if (bx < 2 * NB * NM + TB * NB) {
    // ===== t2 role: decode per (b,a); per-(b,m) partial max; pairmask =====
    int t2i = bx - 2 * NB * NM;
    int b = t2i >> 5;
    int chunk = t2i & 31;
    if (tid < NM) {
      float4 t = tgt[b * NM + tid];
      s_t[tid] = t;
      s_ta[tid] = (t.z - t.x) * (t.w - t.y);
      s_max[tid] = 0u;
    }
    __syncthreads();

    int a = chunk * 1024 + tid;
    float4 p = anc[a];
    float4 l = br[(size_t)b * NA + a];
    float cx = p.x + l.x * VAR0 * p.z;
    float cy = p.y + l.y * VAR0 * p.w;
    float w = p.z * __expf(l.z * VAR1);
    float h = p.w * __expf(l.w * VAR1);
    float dx0 = cx - 0.5f * w, dy0 = cy - 0.5f * h;
    float dx1 = cx + 0.5f * w, dy1 = cy + 0.5f * h;
    float da = (dx1 - dx0) * (dy1 - dy0);

    unsigned mymask = 0u;
#pragma unroll
    for (int mm = 0; mm < NM; ++mm) {
      int m = (tid + mm) & (NM - 1);     // stagger over LDS bins
      float4 t = s_t[m];
      float iou = iou_corner(t.x, t.y, t.z, t.w, s_ta[m], dx0, dy0, dx1, dy1, da);
      if (iou > T1f) mymask |= 1u << m;
      atomicMax(&s_max[m], __float_as_uint(iou));  // iou>=0: uint order == float order
    }
    pairmask[(size_t)b * NA + a] = mymask;
    __syncthreads();
    if (tid < NM)
      partmax[((size_t)b * NM + tid) * TB + chunk] = s_max[tid];  // non-atomic
  }
  // else: f0-only
}

// ---- K2: merge two local top-50s -> exact top-50 + bag loss ----
__global__ void __launch_bounds__(128) posfin_kernel(const float4* __restrict__ br,
                                                     const float* __restrict__ cls,
                                                     const float4* __restrict__ anc,
                                                     const float4* __restrict__ tgt,
                                                     const int* __restrict__ labels,
                                                     const unsigned long long* __restrict__ cand50,
                                                     const unsigned* __restrict__ poscnt,
                                                     const unsigned* __restrict__ zlist,
                                                     const unsigned* __restrict__ zcnt,
                                                     float* __restrict__ posp) {
  __shared__ unsigned long long kbuf[2 * NK];
  __shared__ int sel[NK];
  __shared__ int s_total;
  int bm = blockIdx.x;
  int b = bm >> 5;
  int tid = threadIdx.x;
  float4 t = tgt[bm];

  if (tid < NK) {
    kbuf[tid]      = cand50[(size_t)(bm * 2 + 0) * NK + tid];
    kbuf[NK + tid] = cand50[(size_t)(bm * 2 + 1) * NK + tid];
  }
  if (tid == 0)
    s_total = (int)(poscnt[bm * 2] + poscnt[bm * 2 + 1]);   // exact when < NK
  __syncthreads();

  if (tid < 2 * NK) {
    unsigned long long key = kbuf[tid];
    if (key != 0ull) {                    // real candidates rank above sentinels
      int rank = 0;
      for (int j = 0; j < 2 * NK; ++j) rank += (kbuf[j] > key);
      if (rank < NK) sel[rank] = (int)(~(unsigned)(key & 0xFFFFFFFFull));
    }
  }
  __syncthreads();

  int total = s_total;
  if (total < NK) {                       // degenerate: fill with smallest zero-iou idx
    if (tid == 0) {
      int idx = total;
      unsigned zc0 = zcnt[bm * 2], zc1 = zcnt[bm * 2 + 1];
      for (unsigned j = 0; j < zc0 && idx < NK; ++j) sel[idx++] = (int)zlist[(size_t)(bm * 2) * NK + j];
      for (unsigned j = 0; j < zc1 && idx < NK; ++j) sel[idx++] = (int)zlist[(size_t)(bm * 2 + 1) * NK + j];
    }
    __syncthreads();
  }

  if (tid < 64) {
    int lane = tid;
    float lg = 0.f, wr = 0.f;
    if (lane < NK) {
      int a = sel[lane];
      int lb = labels[bm];
      float4 p = anc[a];
      float4 l = br[(size_t)b * NA + a];
      float logit = cls[((size_t)b * NA + a) * NC + lb];
      float mc = fast_rcp(1.f + __expf(-logit));
      float gx = ((t.x + t.z) * 0.5f - p.x) * fast_rcp(VAR0 * p.z);
      float gy = ((t.y + t.w) * 0.5f - p.y) * fast_rcp(VAR0 * p.w);
      float gw = __logf((t.z - t.x) * fast_rcp(p.z)) * 5.f;   // /VAR1
      float gh = __logf((t.w - t.y) * fast_rcp(p.w)) * 5.f;
      float v0 = gx - l.x, v1 = gy - l.y, v2 = gw - l.z, v3 = gh - l.w;
      float rl = 0.f;
      {
        float av;
        av = fabsf(v0); rl += (av < SL1B) ? (0.5f / SL1B) * v0 * v0 : (av - 0.5f * SL1B);
        av = fabsf(v1); rl += (av < SL1B) ? (0.5f / SL1B) * v1 * v1 : (av - 0.5f * SL1B);
        av = fabsf(v2); rl += (av < SL1B) ? (0.5f / SL1B) * v2 * v2 : (av - 0.5f * SL1B);
        av = fabsf(v3); rl += (av < SL1B) ? (0.5f / SL1B) * v3 * v3 : (av - 0.5f * SL1B);
      }
      rl *= SL1W;
      lg = mc * __expf(-rl);
      wr = fast_rcp(fmaxf(1.f - lg, FEPS));
    }
    float swl = wr * lg, swr = wr;
    for (int off = 32; off; off >>= 1) { swl += __shfl_down(swl, off); swr += __shfl_down(swr, off); }
    if (lane == 0) {
      float bag = swl / swr;
      posp[bm] = -fmaxf(logf(fmaxf(bag, 1e-38f)), -100.f);    // non-atomic partial
    }
  }
}

// ---- K3: sparse correction where bp > 0 (non-atomic partials) ----
__global__ void __launch_bounds__(256) corr_kernel(const float4* __restrict__ br,
                                                   const float* __restrict__ cls,
                                                   const float4* __restrict__ anc,
                                                   const float4* __restrict__ tgt,
                                                   const int* __restrict__ labels,
                                                   const unsigned* __restrict__ partmax,
                                                   const unsigned* __restrict__ pairmask,
                                                   float* __restrict__ corrp) {
  __shared__ float4 s_t[NM];
  __shared__ float s_ta[NM], s_inv[NM];
  __shared__ unsigned s_cmask[NC];
  __shared__ unsigned s_maxm[NM];
  __shared__ unsigned s_slotmask[NM];
  __shared__ int s_slotclass[NM];
  __shared__ int s_nslots;
  int b = blockIdx.y;
  int tid = threadIdx.x;
  if (tid < NC) s_cmask[tid] = 0u;
  if (tid < NM) s_maxm[tid] = 0u;
  if (tid == 0) s_nslots = 0;
  __syncthreads();
  if (tid < NM) {
    float4 t = tgt[b * NM + tid];
    s_t[tid] = t;
    s_ta[tid] = (t.z - t.x) * (t.w - t.y);
    atomicOr(&s_cmask[labels[b * NM + tid]], 1u << tid);
  }
  {
    int m = tid >> 3, j = tid & 7;
    const unsigned* pm = &partmax[((size_t)b * NM + m) * TB];
    unsigned mx = 0u;
    for (int k = j; k < TB; k += 8) mx = max(mx, pm[k]);
    atomicMax(&s_maxm[m], mx);
  }
  __syncthreads();
  if (tid < NM) {
    float mxf = __uint_as_float(s_maxm[tid]);
    s_inv[tid] = 1.0f / (fmaxf(mxf, T1f) - T1f);   // T1+1e-12 rounds to 0.5f in fp32
  }
  __syncthreads();
  if (tid < NC && s_cmask[tid] != 0u) {
    int slot = atomicAdd(&s_nslots, 1);
    s_slotmask[slot] = s_cmask[tid];
    s_slotclass[slot] = tid;
  }
  __syncthreads();
  int nslots = s_nslots;

  int a = blockIdx.x * 256 + tid;
  unsigned mk32 = pairmask[(size_t)b * NA + a];
  float accum = 0.f;
  if (mk32) {
    float4 p = anc[a];
    float4 l = br[(size_t)b * NA + a];
    float cx = p.x + l.x * VAR0 * p.z;
    float cy = p.y + l.y * VAR0 * p.w;
    float w = p.z * __expf(l.z * VAR1);
    float h = p.w * __expf(l.w * VAR1);
    float dx0 = cx - 0.5f * w, dy0 = cy - 0.5f * h;
    float dx1 = cx + 0.5f * w, dy1 = cy + 0.5f * h;
    float da = (dx1 - dx0) * (dy1 - dy0);
    for (int j = 0; j < nslots; ++j) {
      unsigned sm = mk32 & s_slotmask[j];
      if (!sm) continue;
      float bp = 0.f;
      while (sm) {
        int m = __ffs(sm) - 1;
        sm &= sm - 1;
        float4 t = s_t[m];
        float iou = iou_corner(t.x, t.y, t.z, t.w, s_ta[m], dx0, dy0, dx1, dy1, da);
        float o = (iou - T1f) * s_inv[m];
        bp = fmaxf(bp, fminf(fmaxf(o, 0.f), 1.f));
      }
      if (bp > 0.f) {
        float x = cls[((size_t)b * NA + a) * NC + s_slotclass[j]];
        float s = fast_rcp(1.f + __expf(-fmaxf(x, -60.f)));
        float pr = s * (1.f - bp);
        float om = fmaxf(1.f - pr, 1e-38f);
        float fbp = pr * pr * fminf(-__logf(om), 100.f);
        accum += fbp - f0_term(x);          // cancels mega's baseline bit-exactly
      }
    }
  }
  for (int off = 32; off; off >>= 1) accum += __shfl_down(accum, off);
  __shared__ float swv[4];
  if ((tid & 63) == 0) swv[tid >> 6] = accum;
  __syncthreads();
  if (tid == 0)
    corrp[(size_t)b * CORRB + blockIdx.x] = swv[0] + swv[1] + swv[2] + swv[3];  // non-atomic
}

// ---- K4: finalize — sum all partials in double ----
__global__ void __launch_bounds__(256) fin_kernel(const float* __restrict__ posp,
                                                  const float* __restrict__ f0part,
                                                  const float* __restrict__ corrp,
                                                  float* __restrict__ out) {
  int tid = threadIdx.x;
  double sp = 0.0, sn = 0.0;
  for (int i = tid; i < NB * NM; i += 256) sp += (double)posp[i];
  for (int i = tid; i < NBLK; i += 256) sn += (double)f0part[i];
  for (int i = tid; i < NB * CORRB; i += 256) sn += (double)corrp[i];
  for (int off = 32; off; off >>= 1) { sp += __shfl_down(sp, off); sn += __shfl_down(sn, off); }
  __shared__ double swp[4], swn[4];
  if ((tid & 63) == 0) { swp[tid >> 6] = sp; swn[tid >> 6] = sn; }
  __syncthreads();
  if (tid == 0) {
    double pos = swp[0] + swp[1] + swp[2] + swp[3];
    double neg = swn[0] + swn[1] + swn[2] + swn[3];
    out[0] = (float)(pos / 256.0 * 0.5);
    out[1] = (float)(neg / 12800.0 * 0.5);
  }
}

extern "C" void kernel_launch(void* const* d_in, const int* in_sizes, int n_in,
                              void* d_out, int out_size, void* d_ws, size_t ws_size,
                              hipStream_t stream) {
  const float4* br  = (const float4*)d_in[0];
  const float*  cls = (const float*)d_in[1];
  const float4* anc = (const float4*)d_in[2];
  const float4* tgt = (const float4*)d_in[3];
  const int*    lab = (const int*)d_in[4];
  float* out = (float*)d_out;
  // ws layout — written-before-read every call (zlist/zcnt written & read under the
  // same input-dependent condition); no global atomics anywhere -> no init needed:
  float*              posp     = (float*)d_ws;                              // 256 f32
  float*              f0part   = (float*)((char*)d_ws + 4096);              // 1024 f32
  float*              corrp    = (float*)((char*)d_ws + 8192);              // 1024 f32
  unsigned*           poscnt   = (unsigned*)((char*)d_ws + 12288);          // 512 u32
  unsigned*           partmax  = (unsigned*)((char*)d_ws + 16384);          // 8192 u32 = 32 KB
  unsigned long long* cand50   = (unsigned long long*)((char*)d_ws + 49152);// 256*2*50 u64 = 200 KB
  unsigned*           zlist    = (unsigned*)((char*)d_ws + 253952);         // 256*2*50 u32 = 100 KB
  unsigned*           zcnt     = (unsigned*)((char*)d_ws + 356352);         // 512 u32
  unsigned*           pairmask = (unsigned*)((char*)d_ws + 360448);         // NB*NA u32 = 1 MB

  mega_kernel<<<dim3(NBLK), 1024, 0, stream>>>(
      br, cls, anc, tgt, partmax, pairmask, cand50, poscnt, zlist, zcnt, f0part);
  posfin_kernel<<<dim3(NB * NM), 128, 0, stream>>>(
      br, cls, anc, tgt, lab, cand50, poscnt, zlist, zcnt, posp);
  corr_kernel<<<dim3(CORRB, NB), 256, 0, stream>>>(br, cls, anc, tgt, lab, partmax, pairmask, corrp);
  fin_kernel<<<1, 256, 0, stream>>>(posp, f0part, corrp, out);
}